// Round 5
// baseline (560.858 us; speedup 1.0000x reference)
//
#include <hip/hip_runtime.h>
#include <math.h>

#define N_NODES 50000
#define N_EDGES 800000
#define D 128
#define E_DIM 16
#define DEPTH 3

typedef _Float16 half2_t __attribute__((ext_vector_type(2)));
typedef _Float16 half4_t __attribute__((ext_vector_type(4)));
typedef _Float16 half8_t __attribute__((ext_vector_type(8)));
typedef float floatx4 __attribute__((ext_vector_type(4)));

#if defined(__has_builtin)
#if __has_builtin(__builtin_amdgcn_fdot2)
#define FDOT2(a, b, c) __builtin_amdgcn_fdot2((a), (b), (c), false)
#endif
#endif
#ifndef FDOT2
static __device__ __forceinline__ float fdot2_sw(half2_t a, half2_t b, float c) {
    return fmaf((float)a.x, (float)b.x, fmaf((float)a.y, (float)b.y, c));
}
#define FDOT2(a, b, c) fdot2_sw((a), (b), (c))
#endif

// s_waitcnt vmcnt(8), lgkm/exp unconstrained: 8 | (7<<4) | (15<<8) = 0xF78
#define WAIT_VMCNT8() __builtin_amdgcn_s_waitcnt(0xF78)

typedef const void __attribute__((address_space(1)))* gas_ptr;
typedef void __attribute__((address_space(3)))* las_ptr;

// async fetch of one 256-B x-row into LDS (lane i -> byte 4i), no VGPR payload
static __device__ __forceinline__ void fetch_row(const _Float16* xb, int srcrow,
                                                 int lane, _Float16* ldsdst) {
    const char* gp = (const char*)xb + (size_t)srcrow * 256 + lane * 4;
    __builtin_amdgcn_global_load_lds((gas_ptr)(uintptr_t)gp,
                                     (las_ptr)(uintptr_t)ldsdst, 4, 0, 0);
}

// ---------------- CSR build (by dst) ----------------

__global__ void k_hist(const int* __restrict__ dst, int* __restrict__ deg) {
    int e = blockIdx.x * blockDim.x + threadIdx.x;
    if (e < N_EDGES) atomicAdd(&deg[dst[e]], 1);
}

__global__ void k_scan1(const int* __restrict__ deg, int* __restrict__ out1,
                        int* __restrict__ bsum) {
    __shared__ int s[256];
    int t = threadIdx.x;
    int base = blockIdx.x * 1024;
    int v[4]; int sum = 0;
#pragma unroll
    for (int j = 0; j < 4; j++) {
        int idx = base + t * 4 + j;
        int x = (idx < N_NODES) ? deg[idx] : 0;
        v[j] = x; sum += x;
    }
    s[t] = sum;
    __syncthreads();
    for (int d2 = 1; d2 < 256; d2 <<= 1) {
        int val = (t >= d2) ? s[t - d2] : 0;
        __syncthreads();
        s[t] += val;
        __syncthreads();
    }
    int run = (t > 0) ? s[t - 1] : 0;
#pragma unroll
    for (int j = 0; j < 4; j++) {
        int idx = base + t * 4 + j;
        run += v[j];
        if (idx < N_NODES) out1[idx] = run;
    }
    if (t == 255) bsum[blockIdx.x] = s[255];
}

__global__ void k_scanadd(int* __restrict__ off, const int* __restrict__ bsum1,
                          int* __restrict__ head) {
    int i = blockIdx.x * blockDim.x + threadIdx.x;
    if (i == 0) { off[0] = 0; head[0] = 0; }
    if (i < N_NODES) {
        int nb = i >> 10;
        int add = 0;
        for (int j = 0; j < nb; j++) add += bsum1[j];
        int v = off[i + 1] + add;
        off[i + 1] = v;
        if (i + 1 < N_NODES) head[i + 1] = v;
    }
}

__global__ void k_scatter(const int* __restrict__ src, const int* __restrict__ dst,
                          int* __restrict__ head, int2* __restrict__ sorted) {
    int e = blockIdx.x * blockDim.x + threadIdx.x;
    if (e < N_EDGES) {
        int d = dst[e];
        int pos = atomicAdd(&head[d], 1);
        sorted[pos] = make_int2(src[e], e);
    }
}

// ---------------- prep: f16 converts + MFMA weight packing (one kernel) ------

#define NB_X   3125    // N_NODES*D/8/256
#define NB_EA  6250    // N_EDGES*E_DIM/8/256
#define NB_W   384     // 6*16384/256

__global__ void k_prep(const float* __restrict__ x, const float* __restrict__ ea,
                       const float* __restrict__ W1, const float* __restrict__ W2,
                       _Float16* __restrict__ xh, _Float16* __restrict__ eah,
                       _Float16* __restrict__ Wp) {
    int b = blockIdx.x;
    if (b < NB_X + NB_EA) {
        const float* in = (b < NB_X) ? x : ea;
        _Float16* out = (b < NB_X) ? xh : eah;
        int i = (b < NB_X) ? (b * 256 + threadIdx.x) : ((b - NB_X) * 256 + threadIdx.x);
        int base = i * 8;
        float4 a = *(const float4*)(in + base);
        float4 c = *(const float4*)(in + base + 4);
        half8_t h = {(_Float16)a.x, (_Float16)a.y, (_Float16)a.z, (_Float16)a.w,
                     (_Float16)c.x, (_Float16)c.y, (_Float16)c.z, (_Float16)c.w};
        *(half8_t*)(out + base) = h;
    } else {
        int t = (b - NB_X - NB_EA) * 256 + threadIdx.x;
        int j    = t & 7;
        int lane = (t >> 3) & 63;
        int nb   = (t >> 9) & 7;
        int kb   = (t >> 12) & 3;
        int mat  = t >> 14;
        int layer = mat >> 1, which = mat & 1;
        const float* Wsrc = (which ? W2 : W1) + (size_t)layer * D * D;
        int k = kb * 32 + (lane >> 4) * 8 + j;
        int n = nb * 16 + (lane & 15);
        Wp[t] = (_Float16)Wsrc[k * D + n];
    }
}

// ---------------- per-layer: aggregation ----------------
// One wave per dst node; 2 groups x 32 lanes; lane = 4 feats.
// Edges in batches of 8; x-rows async-gathered into a per-wave LDS double
// buffer via global_load_lds (zero VGPR in-flight cost); explicit
// s_waitcnt vmcnt(8) keeps the next batch's 8 fetches in flight across the
// compute phase. Uniform control flow; tail edges predicated at accumulate.

__global__ __launch_bounds__(256) void k_agg(
    const _Float16* __restrict__ xb, const _Float16* __restrict__ eah,
    const int2* __restrict__ sorted, const int* __restrict__ off,
    const float* __restrict__ We_l, const float* __restrict__ be_l,
    const float* __restrict__ eps_ptr, _Float16* __restrict__ h0) {
    __shared__ _Float16 ring[4][2][8][128];   // 16 KB / block
    int w = threadIdx.x >> 6;
    int n = blockIdx.x * 4 + w;
    if (n >= N_NODES) return;
    int lane = threadIdx.x & 63;
    int g = lane >> 5;        // group 0/1
    int c = lane & 31;        // feats 4c..4c+3

    half2_t w2[8][4];
    float bev[4];
    {
        float4 bb = *(const float4*)(be_l + 4 * c);
        bev[0] = bb.x; bev[1] = bb.y; bev[2] = bb.z; bev[3] = bb.w;
#pragma unroll
        for (int kp = 0; kp < 8; kp++) {
            float4 r0 = *(const float4*)(We_l + (2 * kp) * D + 4 * c);
            float4 r1 = *(const float4*)(We_l + (2 * kp + 1) * D + 4 * c);
            w2[kp][0] = half2_t{(_Float16)r0.x, (_Float16)r1.x};
            w2[kp][1] = half2_t{(_Float16)r0.y, (_Float16)r1.y};
            w2[kp][2] = half2_t{(_Float16)r0.z, (_Float16)r1.z};
            w2[kp][3] = half2_t{(_Float16)r0.w, (_Float16)r1.w};
        }
    }

    float acc[4] = {0.f, 0.f, 0.f, 0.f};
    int t0 = __builtin_amdgcn_readfirstlane(off[n]);
    int t1 = __builtin_amdgcn_readfirstlane(off[n + 1]);
    int deg = t1 - t0;

    if (deg > 0) {
        int nbatch = (deg + 7) >> 3;
        int i0 = t0 + (lane & 7);

        // ---- prolog: indices for batch 0, issue its 8 fetches ----
        int2 svB = sorted[min(i0, N_EDGES - 1)];
        int ecur0 = __shfl(svB.y, g * 4 + 0, 64);
        int ecur1 = __shfl(svB.y, g * 4 + 1, 64);
        int ecur2 = __shfl(svB.y, g * 4 + 2, 64);
        int ecur3 = __shfl(svB.y, g * 4 + 3, 64);
        {
            int sj[8];
#pragma unroll
            for (int j = 0; j < 8; j++) sj[j] = __builtin_amdgcn_readlane(svB.x, j);
#pragma unroll
            for (int j = 0; j < 8; j++)
                fetch_row(xb, sj[j], lane, &ring[w][0][j][0]);
        }
        svB = sorted[min(i0 + 8, N_EDGES - 1)];   // indices for batch 1

        for (int b = 0; b < nbatch; b++) {
            int buf = b & 1;
            int tb = t0 + b * 8;

            // 1) extract batch b+1 indices (svB loaded last iter / prolog)
            int sj[8];
#pragma unroll
            for (int j = 0; j < 8; j++) sj[j] = __builtin_amdgcn_readlane(svB.x, j);
            int en0 = __shfl(svB.y, g * 4 + 0, 64);
            int en1 = __shfl(svB.y, g * 4 + 1, 64);
            int en2 = __shfl(svB.y, g * 4 + 2, 64);
            int en3 = __shfl(svB.y, g * 4 + 3, 64);
            // 2) sorted vector for batch b+2
            svB = sorted[min(i0 + (b + 2) * 8, N_EDGES - 1)];
            // 3) edge-attr for batch b (group-local rows, L1-broadcast)
            half8_t lo0 = *(const half8_t*)(eah + (size_t)ecur0 * E_DIM);
            half8_t hi0 = *(const half8_t*)(eah + (size_t)ecur0 * E_DIM + 8);
            half8_t lo1 = *(const half8_t*)(eah + (size_t)ecur1 * E_DIM);
            half8_t hi1 = *(const half8_t*)(eah + (size_t)ecur1 * E_DIM + 8);
            half8_t lo2 = *(const half8_t*)(eah + (size_t)ecur2 * E_DIM);
            half8_t hi2 = *(const half8_t*)(eah + (size_t)ecur2 * E_DIM + 8);
            half8_t lo3 = *(const half8_t*)(eah + (size_t)ecur3 * E_DIM);
            half8_t hi3 = *(const half8_t*)(eah + (size_t)ecur3 * E_DIM + 8);
            // 4) issue batch b+1 x-row fetches into the other buffer
#pragma unroll
            for (int j = 0; j < 8; j++)
                fetch_row(xb, sj[j], lane, &ring[w][buf ^ 1][j][0]);
            // 5) retire batch-b fetches + ea; keep batch-b+1 fetches in flight
            WAIT_VMCNT8();
            __builtin_amdgcn_sched_barrier(0);
            // 6) compute 8 edges (4 per group) from LDS + ea regs
            auto do_edge = [&](half8_t lo, half8_t hi, int j) {
                int slot = g * 4 + j;
                half4_t xv = *(const half4_t*)&ring[w][buf][slot][c * 4];
                float p0 = bev[0], p1 = bev[1], p2 = bev[2], p3 = bev[3];
#pragma unroll
                for (int kp = 0; kp < 4; kp++) {
                    half2_t e2 = half2_t{lo[2 * kp], lo[2 * kp + 1]};
                    p0 = FDOT2(e2, w2[kp][0], p0);
                    p1 = FDOT2(e2, w2[kp][1], p1);
                    p2 = FDOT2(e2, w2[kp][2], p2);
                    p3 = FDOT2(e2, w2[kp][3], p3);
                }
#pragma unroll
                for (int kp = 0; kp < 4; kp++) {
                    half2_t e2 = half2_t{hi[2 * kp], hi[2 * kp + 1]};
                    p0 = FDOT2(e2, w2[kp + 4][0], p0);
                    p1 = FDOT2(e2, w2[kp + 4][1], p1);
                    p2 = FDOT2(e2, w2[kp + 4][2], p2);
                    p3 = FDOT2(e2, w2[kp + 4][3], p3);
                }
                bool valid = (tb + slot) < t1;
                float m0 = fmaxf((float)xv[0] + p0, 0.f);
                float m1 = fmaxf((float)xv[1] + p1, 0.f);
                float m2 = fmaxf((float)xv[2] + p2, 0.f);
                float m3 = fmaxf((float)xv[3] + p3, 0.f);
                acc[0] += valid ? m0 : 0.f;
                acc[1] += valid ? m1 : 0.f;
                acc[2] += valid ? m2 : 0.f;
                acc[3] += valid ? m3 : 0.f;
            };
            do_edge(lo0, hi0, 0);
            do_edge(lo1, hi1, 1);
            do_edge(lo2, hi2, 2);
            do_edge(lo3, hi3, 3);
            // 7) rotate edge ids
            ecur0 = en0; ecur1 = en1; ecur2 = en2; ecur3 = en3;
        }
    }

    // cross-group reduction: lane l += lane l^32
#pragma unroll
    for (int f = 0; f < 4; f++) acc[f] += __shfl_xor(acc[f], 32, 64);

    if (g == 0) {
        float epsv = 1.0f + eps_ptr[0];
        half4_t xv = *(const half4_t*)(xb + (size_t)n * D + 4 * c);
        half4_t oh;
#pragma unroll
        for (int f = 0; f < 4; f++)
            oh[f] = (_Float16)(fmaf(epsv, (float)xv[f], acc[f]));
        *(half4_t*)(h0 + (size_t)n * D + 4 * c) = oh;
    }
}

// ---------------- per-layer: fused node MLP via MFMA f16 ----------------

template <bool LAST>
__global__ __launch_bounds__(256) void k_mlp(
    const _Float16* __restrict__ h0, const _Float16* __restrict__ W1p,
    const float* __restrict__ b1, const _Float16* __restrict__ W2p,
    const float* __restrict__ b2, float* __restrict__ outf,
    _Float16* __restrict__ outh) {
    __shared__ _Float16 sH[64 * 136];
    __shared__ _Float16 sG[64 * 136];
    int n0 = blockIdx.x * 64;
    int t = threadIdx.x;

    for (int cc = t; cc < 1024; cc += 256) {
        int row = cc >> 4, c4 = cc & 15;
        uint4 v = make_uint4(0, 0, 0, 0);
        if (n0 + row < N_NODES)
            v = *(const uint4*)(h0 + (size_t)(n0 + row) * D + c4 * 8);
        *(uint4*)&sH[row * 136 + c4 * 8] = v;
    }
    __syncthreads();

    int w = t >> 6, lane = t & 63, q = lane >> 4, r16 = lane & 15;
    int mrow = w * 16 + r16;

    floatx4 acc[8];
#pragma unroll
    for (int nb = 0; nb < 8; nb++) acc[nb] = floatx4{0.f, 0.f, 0.f, 0.f};
#pragma unroll
    for (int kb = 0; kb < 4; kb++) {
        half8_t av = *(const half8_t*)&sH[mrow * 136 + kb * 32 + q * 8];
#pragma unroll
        for (int nb = 0; nb < 8; nb++) {
            half8_t bv = *(const half8_t*)(W1p + (size_t)((kb * 8 + nb) * 64 + lane) * 8);
            acc[nb] = __builtin_amdgcn_mfma_f32_16x16x32_f16(av, bv, acc[nb], 0, 0, 0);
        }
    }
#pragma unroll
    for (int nb = 0; nb < 8; nb++) {
        int col = nb * 16 + r16;
        float bb = b1[col];
#pragma unroll
        for (int r = 0; r < 4; r++) {
            float v = acc[nb][r] + bb;
            float gl = 0.5f * v * (1.0f + erff(v * 0.70710678118654752f));
            sG[(w * 16 + q * 4 + r) * 136 + col] = (_Float16)gl;
        }
    }
    // wave w writes exactly the sG rows it reads below — no barrier needed

#pragma unroll
    for (int nb = 0; nb < 8; nb++) acc[nb] = floatx4{0.f, 0.f, 0.f, 0.f};
#pragma unroll
    for (int kb = 0; kb < 4; kb++) {
        half8_t av = *(const half8_t*)&sG[mrow * 136 + kb * 32 + q * 8];
#pragma unroll
        for (int nb = 0; nb < 8; nb++) {
            half8_t bv = *(const half8_t*)(W2p + (size_t)((kb * 8 + nb) * 64 + lane) * 8);
            acc[nb] = __builtin_amdgcn_mfma_f32_16x16x32_f16(av, bv, acc[nb], 0, 0, 0);
        }
    }
#pragma unroll
    for (int nb = 0; nb < 8; nb++) {
        int col = nb * 16 + r16;
        float bb = b2[col];
#pragma unroll
        for (int r = 0; r < 4; r++) {
            int n = n0 + w * 16 + q * 4 + r;
            if (n < N_NODES) {
                float v = acc[nb][r] + bb;
                if (LAST) outf[(size_t)n * D + col] = v;
                else      outh[(size_t)n * D + col] = (_Float16)v;
            }
        }
    }
}

// ---------------- launch ----------------

static inline size_t align_up(size_t v, size_t a) { return (v + a - 1) & ~(a - 1); }

extern "C" void kernel_launch(void* const* d_in, const int* in_sizes, int n_in,
                              void* d_out, int out_size, void* d_ws, size_t ws_size,
                              hipStream_t stream) {
    const float* x         = (const float*)d_in[0];
    const float* edge_attr = (const float*)d_in[1];
    const float* W1        = (const float*)d_in[2];
    const float* b1        = (const float*)d_in[3];
    const float* W2        = (const float*)d_in[4];
    const float* b2        = (const float*)d_in[5];
    const float* We        = (const float*)d_in[6];
    const float* be        = (const float*)d_in[7];
    const float* eps       = (const float*)d_in[8];
    const int*   src       = (const int*)d_in[9];
    const int*   dst       = ((const int*)d_in[9]) + N_EDGES;

    char* w = (char*)d_ws;
    int*  off    = (int*)w;  w += align_up((N_NODES + 1) * sizeof(int), 16);
    int*  deg    = (int*)w;  w += align_up(N_NODES * sizeof(int), 16);
    int*  head   = (int*)w;  w += align_up(N_NODES * sizeof(int), 16);
    int*  bsum   = (int*)w;  w += 256;
    int2* sorted = (int2*)w; w += (size_t)N_EDGES * sizeof(int2);
    _Float16* xb0 = (_Float16*)w; w += (size_t)N_NODES * D * 2;
    _Float16* xb1 = (_Float16*)w; w += (size_t)N_NODES * D * 2;
    _Float16* h0b = (_Float16*)w; w += (size_t)N_NODES * D * 2;
    _Float16* eah = (_Float16*)w; w += (size_t)N_EDGES * E_DIM * 2;
    _Float16* Wp  = (_Float16*)w; w += (size_t)6 * 16384 * 2;

    // ---- CSR build ----
    hipMemsetAsync(deg, 0, N_NODES * sizeof(int), stream);
    k_hist<<<(N_EDGES + 255) / 256, 256, 0, stream>>>(dst, deg);
    int nb1 = (N_NODES + 1023) / 1024;
    k_scan1<<<nb1, 256, 0, stream>>>(deg, off + 1, bsum);
    k_scanadd<<<(N_NODES + 255) / 256, 256, 0, stream>>>(off, bsum, head);
    k_scatter<<<(N_EDGES + 255) / 256, 256, 0, stream>>>(src, dst, head, sorted);

    // ---- prep: converts + weight packing ----
    k_prep<<<NB_X + NB_EA + NB_W, 256, 0, stream>>>(x, edge_attr, W1, W2, xb0, eah, Wp);

    // ---- 3 layers ----
    _Float16* xcur = xb0;
    _Float16* xnxt = xb1;
    for (int l = 0; l < DEPTH; l++) {
        k_agg<<<(N_NODES + 3) / 4, 256, 0, stream>>>(
            xcur, eah, sorted, off,
            We + (size_t)l * E_DIM * D, be + (size_t)l * D, eps + l, h0b);
        const _Float16* W1p = Wp + (size_t)(l * 2 + 0) * 16384;
        const _Float16* W2p = Wp + (size_t)(l * 2 + 1) * 16384;
        if (l == DEPTH - 1) {
            k_mlp<true><<<(N_NODES + 63) / 64, 256, 0, stream>>>(
                h0b, W1p, b1 + (size_t)l * D, W2p, b2 + (size_t)l * D,
                (float*)d_out, nullptr);
        } else {
            k_mlp<false><<<(N_NODES + 63) / 64, 256, 0, stream>>>(
                h0b, W1p, b1 + (size_t)l * D, W2p, b2 + (size_t)l * D,
                nullptr, xnxt);
        }
        _Float16* tmp = xcur; xcur = xnxt; xnxt = tmp;
    }
}